// Round 12
// baseline (422.033 us; speedup 1.0000x reference)
//
#include <hip/hip_runtime.h>
#include <hip/hip_bf16.h>

// N = 100000, E = 1600000, IN = 128, H = 4, D = 32
//
// Math (validated rounds 1-11, absmax 1.95e-3 vs threshold 8.2e-3):
//   vbar[n]  = xs[n] @ WT^T + bvbar          (WT[d][i] = 0.25*sum_h Wv[i][32h+d])
//   vbar2[n] = vbar[n] * (deg[n]? rsqrt(deg[n]) : 0)       [bf16, scaled in place]
//   cst[d]   = mean_n vbar[n,d]   (f32 accumulation pre-rounding)
//   out[n,d] = cst[d] + (deg[n]? rsqrt(deg[n]):0) * sum_{e:col=n} vbar2[row_e, d]
//
// Round-12 structure (6 kernels, minimal serial chain):
//   wt      : pack MFMA B fragments + zero g_csum
//   fused   : vbar MFMA (unscaled bf16 + csum)  ||  per-block bucket histogram
//   scanPB  : per-bucket scan over blocks -> partial_pb, colsum
//   fill    : LDS scan of colsum -> bucketBase; private cursors -> sorted
//   scale   : per-bucket histogram -> deg; vbarb *= rsqrt(deg) in place
//   gather  : per-bucket LDS acc[128][32] via ds-atomics off bucket-grouped
//             sorted (no sorted2/rowptr/rsd buffers at all)

#define GRID_EDGE 512
#define MAXBUK 1024   // supports N <= 131072

typedef __attribute__((ext_vector_type(8))) short    short8v;
typedef __attribute__((ext_vector_type(8))) __bf16   bf16x8;
typedef __attribute__((ext_vector_type(4))) float    f32x4;

__device__ __forceinline__ short f2bf(float f) {
    unsigned u = __float_as_uint(f);
    unsigned r = (u + 0x7FFFu + ((u >> 16) & 1u)) >> 16;   // RNE
    return (short)r;
}
__device__ __forceinline__ float bf2f(unsigned short v) {
    return __uint_as_float((unsigned)v << 16);
}

// ---------------------------------------------------------------------------
// K0: pack B fragments + zero g_csum. WTB[((dt*4+kt)*64+l)*8+j] = bf16(wt(k,d)),
//     k = kt*32 + (l>>4)*8 + j, d = dt*16 + (l&15),
//     wt(i,d) = 0.25*sum_h Wv[i*128+32h+d].
// ---------------------------------------------------------------------------
__global__ __launch_bounds__(256) void wt_kernel(const float* __restrict__ Wv,
                                                 short* __restrict__ WTB,
                                                 float* __restrict__ g_csum) {
    int idx = blockIdx.x * 256 + threadIdx.x;
    if (blockIdx.x == 0 && threadIdx.x < 32) g_csum[threadIdx.x] = 0.f;
    if (idx < 512) {
        int l = idx & 63;
        int kt = (idx >> 6) & 3;
        int dt = idx >> 8;
        int d = dt * 16 + (l & 15);
        int kbase = kt * 32 + (l >> 4) * 8;
#pragma unroll
        for (int j = 0; j < 8; j++) {
            int i = kbase + j;
            float w = 0.25f * (Wv[i * 128 + d] + Wv[i * 128 + 32 + d] +
                               Wv[i * 128 + 64 + d] + Wv[i * 128 + 96 + d]);
            WTB[idx * 8 + j] = f2bf(w);
        }
    }
}

// ---------------------------------------------------------------------------
// K1 (fused): blocks [0, VB): vbar (MFMA, unscaled bf16 + csum)
//             blocks [VB, VB+GRID_EDGE): per-block LDS bucket histogram
// ---------------------------------------------------------------------------
__global__ __launch_bounds__(256) void fused_kernel(
    const float* __restrict__ xs, const short* __restrict__ WTB,
    const float* __restrict__ bv, unsigned short* __restrict__ vbarb,
    float* __restrict__ g_csum, int N, int VB,
    const int* __restrict__ ei, int E, int chunk, int NBUK,
    unsigned* __restrict__ bcnt_pb)
{
    __shared__ float csum_lds[32];
    __shared__ unsigned h[MAXBUK];
    const int tid = threadIdx.x;

    if ((int)blockIdx.x >= VB) {
        // ---------------- histogram part ----------------
        const int p = blockIdx.x - VB;
        for (int k = tid; k < NBUK; k += 256) h[k] = 0u;
        __syncthreads();
        const int e0 = p * chunk;
        const int e1 = min(E, e0 + chunk);
        for (int e = e0 + tid; e < e1; e += 256)
            atomicAdd(&h[ei[E + e] >> 7], 1u);
        __syncthreads();
        unsigned* dst = bcnt_pb + (size_t)p * NBUK;
        for (int k = tid; k < NBUK; k += 256) dst[k] = h[k];
        return;
    }

    // ---------------- vbar part ----------------
    if (tid < 32) csum_lds[tid] = 0.f;

    const int lane = tid & 63;
    const int col = lane & 15;
    const int grp = lane >> 4;

    short8v bfr[2][4];
    const short8v* wtb = (const short8v*)WTB;
#pragma unroll
    for (int dt = 0; dt < 2; dt++)
#pragma unroll
        for (int kt = 0; kt < 4; kt++)
            bfr[dt][kt] = wtb[(dt * 4 + kt) * 64 + lane];

    const int d0 = col, d1 = col + 16;
    const float bb0 = 0.25f * (bv[d0] + bv[32 + d0] + bv[64 + d0] + bv[96 + d0]);
    const float bb1 = 0.25f * (bv[d1] + bv[32 + d1] + bv[64 + d1] + bv[96 + d1]);

    float cs0 = 0.f, cs1 = 0.f;
    const int ntiles = (N + 15) >> 4;
    const int wglob = blockIdx.x * 4 + (tid >> 6);
    const int nwaves = VB * 4;

    for (int t = wglob; t < ntiles; t += nwaves) {
        const int n0 = t * 16;
        const int rowg = min(n0 + col, N - 1);
        const float* xb = xs + (size_t)rowg * 128 + grp * 8;

        f32x4 alo[4], ahi[4];
#pragma unroll
        for (int kt = 0; kt < 4; kt++) {
            alo[kt] = *(const f32x4*)(xb + kt * 32);
            ahi[kt] = *(const f32x4*)(xb + kt * 32 + 4);
        }

        f32x4 acc0 = {0.f, 0.f, 0.f, 0.f};
        f32x4 acc1 = {0.f, 0.f, 0.f, 0.f};
#pragma unroll
        for (int kt = 0; kt < 4; kt++) {
            short8v af;
            af[0] = f2bf(alo[kt][0]); af[1] = f2bf(alo[kt][1]);
            af[2] = f2bf(alo[kt][2]); af[3] = f2bf(alo[kt][3]);
            af[4] = f2bf(ahi[kt][0]); af[5] = f2bf(ahi[kt][1]);
            af[6] = f2bf(ahi[kt][2]); af[7] = f2bf(ahi[kt][3]);
            bf16x8 a = __builtin_bit_cast(bf16x8, af);
            acc0 = __builtin_amdgcn_mfma_f32_16x16x32_bf16(
                a, __builtin_bit_cast(bf16x8, bfr[0][kt]), acc0, 0, 0, 0);
            acc1 = __builtin_amdgcn_mfma_f32_16x16x32_bf16(
                a, __builtin_bit_cast(bf16x8, bfr[1][kt]), acc1, 0, 0, 0);
        }

        const int rbase = n0 + grp * 4;
        const bool full = (n0 + 16 <= N);
#pragma unroll
        for (int r = 0; r < 4; r++) {
            int n = rbase + r;
            if (full || n < N) {
                float v0 = acc0[r] + bb0;
                float v1 = acc1[r] + bb1;
                vbarb[(size_t)n * 32 + d0] = (unsigned short)f2bf(v0);
                vbarb[(size_t)n * 32 + d1] = (unsigned short)f2bf(v1);
                cs0 += v0; cs1 += v1;
            }
        }
    }

    __syncthreads();
    atomicAdd(&csum_lds[d0], cs0);
    atomicAdd(&csum_lds[d1], cs1);
    __syncthreads();
    if (tid < 32) atomicAdd(&g_csum[tid], csum_lds[tid]);
}

// ---------------------------------------------------------------------------
// K2: per-bucket exclusive scan over the 512 blocks in XCD-major logical
// order i (p(i) = (i>>6) + ((i&63)<<3)).  -> partial_pb[bucket][512], colsum.
// ---------------------------------------------------------------------------
__global__ __launch_bounds__(256) void scanPB_kernel(const unsigned* __restrict__ bcnt_pb,
                                                     int NBUK,
                                                     unsigned* __restrict__ partial_pb,
                                                     unsigned* __restrict__ colsum) {
    __shared__ unsigned s[256];
    const int b = blockIdx.x;
    const int tid = threadIdx.x;
    const int i0 = tid * 2, i1 = tid * 2 + 1;
    const int p0 = (i0 >> 6) + ((i0 & 63) << 3);
    const int p1 = (i1 >> 6) + ((i1 & 63) << 3);
    unsigned v0 = bcnt_pb[(size_t)p0 * NBUK + b];
    unsigned v1 = bcnt_pb[(size_t)p1 * NBUK + b];
    unsigned local = v0 + v1;
    s[tid] = local;
    __syncthreads();
    for (int off = 1; off < 256; off <<= 1) {
        unsigned t = (tid >= off) ? s[tid - off] : 0u;
        __syncthreads();
        s[tid] += t;
        __syncthreads();
    }
    unsigned run = s[tid] - local;
    partial_pb[(size_t)b * 512 + i0] = run;
    partial_pb[(size_t)b * 512 + i1] = run + v0;
    if (tid == 255) colsum[b] = s[255];
}

// ---------------------------------------------------------------------------
// K3: fill. Prologue: LDS exclusive scan of colsum -> bucketBase; cursors
// cur[k] = base[k] + partial_pb[k][i(p)], i(p) = (p&7)*64 + (p>>3).
// Then scatter edges to bucket-grouped meta (row | (col&127)<<20).
// ---------------------------------------------------------------------------
__global__ __launch_bounds__(256) void fill_kernel(const int* __restrict__ ei, int E,
                                                   int chunk, int NBUK,
                                                   const unsigned* __restrict__ partial_pb,
                                                   const unsigned* __restrict__ colsum,
                                                   unsigned* __restrict__ sorted) {
    __shared__ unsigned cur[MAXBUK];
    __shared__ unsigned stmp[256];
    const int tid = threadIdx.x;
    const int p = blockIdx.x;
    const int i = (p & 7) * 64 + (p >> 3);

    unsigned v[4], local = 0;
#pragma unroll
    for (int j = 0; j < 4; j++) {
        int k = tid * 4 + j;
        v[j] = (k < NBUK) ? colsum[k] : 0u;
        local += v[j];
    }
    stmp[tid] = local;
    __syncthreads();
    for (int off = 1; off < 256; off <<= 1) {
        unsigned t = (tid >= off) ? stmp[tid - off] : 0u;
        __syncthreads();
        stmp[tid] += t;
        __syncthreads();
    }
    unsigned run = stmp[tid] - local;
#pragma unroll
    for (int j = 0; j < 4; j++) {
        int k = tid * 4 + j;
        if (k < NBUK) cur[k] = run + partial_pb[(size_t)k * 512 + i];
        run += v[j];
    }
    __syncthreads();

    const int e0 = p * chunk;
    const int e1 = min(E, e0 + chunk);
    for (int e = e0 + tid; e < e1; e += 256) {
        int row = ei[e];
        int col = ei[E + e];
        unsigned pos = atomicAdd(&cur[col >> 7], 1u);
        sorted[pos] = (unsigned)row | ((unsigned)(col & 127) << 20);
    }
}

// ---------------------------------------------------------------------------
// K4: scale. Per bucket: [s,e) from colsum prefix; histogram -> deg;
// vbarb rows [b*128, b*128+128) *= rsqrt(deg) in place.
// ---------------------------------------------------------------------------
__global__ __launch_bounds__(256) void scale_kernel(
    const unsigned* __restrict__ colsum, const unsigned* __restrict__ sorted,
    unsigned short* __restrict__ vbarb, int N, int NBUK)
{
    __shared__ unsigned sb[2];
    __shared__ unsigned h[128];
    __shared__ float rs_l[128];
    const int tid = threadIdx.x;
    const int b = blockIdx.x;
    if (tid == 0) sb[0] = 0u;
    if (tid < 128) h[tid] = 0u;
    __syncthreads();
    unsigned part = 0;
    for (int k = tid; k < NBUK; k += 256) {
        unsigned c = colsum[k];
        if (k < b) part += c;
        else if (k == b) sb[1] = c;
    }
    atomicAdd(&sb[0], part);
    __syncthreads();
    const unsigned s = sb[0];
    const unsigned e = s + sb[1];
    for (unsigned p = s + (unsigned)tid; p < e; p += 256u)
        atomicAdd(&h[sorted[p] >> 20], 1u);
    __syncthreads();
    if (tid < 128) rs_l[tid] = h[tid] ? rsqrtf((float)h[tid]) : 0.f;
    __syncthreads();
    const int nbase = b * 128;
#pragma unroll
    for (int it = 0; it < 16; it++) {
        int idx = it * 256 + tid;
        int cl = idx >> 5, d = idx & 31;
        int n = nbase + cl;
        if (n < N) {
            size_t off = (size_t)n * 32 + d;
            vbarb[off] = (unsigned short)f2bf(bf2f(vbarb[off]) * rs_l[cl]);
        }
    }
}

// ---------------------------------------------------------------------------
// K5: gather. Per bucket: stream bucket-grouped meta; lane d accumulates
// scaled vbarb[row][d] into acc[cl][d] via bank-perfect ds-atomics
// (bank = d). 8 edges/iter, unroll 4 -> 32 random 64B lines in flight.
// Epilogue: out[n,d] = cst[d] + rsqrt(deg)*acc.
// ---------------------------------------------------------------------------
__global__ __launch_bounds__(256) void gather_kernel(
    const unsigned* __restrict__ colsum, const unsigned* __restrict__ sorted,
    const unsigned short* __restrict__ vbarb, const float* __restrict__ g_csum,
    float* __restrict__ out, int N, int NBUK, float invN)
{
    __shared__ float acc[4096];
    __shared__ unsigned h[128];
    __shared__ unsigned sb[2];
    const int tid = threadIdx.x;
    const int b = blockIdx.x;
    if (tid == 0) sb[0] = 0u;
    if (tid < 128) h[tid] = 0u;
    for (int k = tid; k < 4096; k += 256) acc[k] = 0.f;
    __syncthreads();
    unsigned part = 0;
    for (int k = tid; k < NBUK; k += 256) {
        unsigned c = colsum[k];
        if (k < b) part += c;
        else if (k == b) sb[1] = c;
    }
    atomicAdd(&sb[0], part);
    __syncthreads();
    const unsigned s = sb[0];
    const unsigned e = s + sb[1];
    const int g = tid >> 5, d = tid & 31;

    unsigned p = s + (unsigned)g;
    for (; p + 24 < e; p += 32) {
        unsigned m0 = sorted[p];
        unsigned m1 = sorted[p + 8];
        unsigned m2 = sorted[p + 16];
        unsigned m3 = sorted[p + 24];
        float f0 = bf2f(vbarb[(size_t)(m0 & 0xFFFFFu) * 32 + d]);
        float f1 = bf2f(vbarb[(size_t)(m1 & 0xFFFFFu) * 32 + d]);
        float f2 = bf2f(vbarb[(size_t)(m2 & 0xFFFFFu) * 32 + d]);
        float f3 = bf2f(vbarb[(size_t)(m3 & 0xFFFFFu) * 32 + d]);
        if (d == 0) {
            atomicAdd(&h[m0 >> 20], 1u);
            atomicAdd(&h[m1 >> 20], 1u);
            atomicAdd(&h[m2 >> 20], 1u);
            atomicAdd(&h[m3 >> 20], 1u);
        }
        atomicAdd(&acc[(m0 >> 20) * 32 + d], f0);
        atomicAdd(&acc[(m1 >> 20) * 32 + d], f1);
        atomicAdd(&acc[(m2 >> 20) * 32 + d], f2);
        atomicAdd(&acc[(m3 >> 20) * 32 + d], f3);
    }
    for (; p < e; p += 8) {
        unsigned m0 = sorted[p];
        float f0 = bf2f(vbarb[(size_t)(m0 & 0xFFFFFu) * 32 + d]);
        if (d == 0) atomicAdd(&h[m0 >> 20], 1u);
        atomicAdd(&acc[(m0 >> 20) * 32 + d], f0);
    }
    __syncthreads();

    const int nbase = b * 128;
#pragma unroll
    for (int it = 0; it < 16; it++) {
        int idx = it * 256 + tid;
        int cl = idx >> 5, dd = idx & 31;
        int n = nbase + cl;
        if (n < N) {
            unsigned hv = h[cl];
            float rv = hv ? rsqrtf((float)hv) : 0.f;
            out[(size_t)n * 32 + dd] = g_csum[dd] * invN + rv * acc[idx];
        }
    }
}

// ---------------------------------------------------------------------------
extern "C" void kernel_launch(void* const* d_in, const int* in_sizes, int n_in,
                              void* d_out, int out_size, void* d_ws, size_t ws_size,
                              hipStream_t stream) {
    const float* xs = (const float*)d_in[1];
    const int*   ei = (const int*)d_in[2];
    const float* Wv = (const float*)d_in[7];
    const float* bv = (const float*)d_in[8];
    float* out = (float*)d_out;

    const int N = in_sizes[0] / 128;
    const int E = in_sizes[2] / 2;
    const int NBUK = (N + 127) >> 7;                 // 782
    const int chunk = (E + GRID_EDGE - 1) / GRID_EDGE;
    const int VB = 1563;                             // vbar blocks in fused kernel

    char* ws = (char*)d_ws;
    size_t o = 0;
    unsigned short* vbarb = (unsigned short*)(ws + o); o += (size_t)N * 32 * 2;
    o = (o + 15) & ~(size_t)15;
    float*    g_csum     = (float*)(ws + o);    o += 32 * 4;
    unsigned* bcnt_pb    = (unsigned*)(ws + o); o += (size_t)GRID_EDGE * NBUK * 4;
    unsigned* partial_pb = (unsigned*)(ws + o); o += (size_t)NBUK * 512 * 4;
    unsigned* colsum     = (unsigned*)(ws + o); o += (size_t)NBUK * 4;
    o = (o + 15) & ~(size_t)15;
    short*    WTB        = (short*)(ws + o);    o += 4096 * 2;
    unsigned* sorted     = (unsigned*)(ws + o); o += (size_t)E * 4;

    wt_kernel<<<2, 256, 0, stream>>>(Wv, WTB, g_csum);
    fused_kernel<<<VB + GRID_EDGE, 256, 0, stream>>>(xs, WTB, bv, vbarb, g_csum,
                                                     N, VB, ei, E, chunk, NBUK, bcnt_pb);
    scanPB_kernel<<<NBUK, 256, 0, stream>>>(bcnt_pb, NBUK, partial_pb, colsum);
    fill_kernel<<<GRID_EDGE, 256, 0, stream>>>(ei, E, chunk, NBUK, partial_pb,
                                               colsum, sorted);
    scale_kernel<<<NBUK, 256, 0, stream>>>(colsum, sorted, vbarb, N, NBUK);
    gather_kernel<<<NBUK, 256, 0, stream>>>(colsum, sorted, vbarb, g_csum,
                                            out, N, NBUK, 1.0f / (float)N);
}

// Round 13
// 110.132 us; speedup vs baseline: 3.8321x; 3.8321x over previous
//
#include <hip/hip_runtime.h>
#include <hip/hip_bf16.h>

// N = 100000, E = 1600000, IN = 128, H = 4, D = 32
//
// Math (validated rounds 1-12, absmax 1.95e-3 vs threshold 8.2e-3):
//   vbar[n]  = xs[n] @ WT^T + bvbar          (WT[d][i] = 0.25*sum_h Wv[i][32h+d])
//   vbar2[n] = vbar[n] * (deg[n]? rsqrt(deg[n]) : 0)       [bf16, scaled in sort]
//   cst[d]   = mean_n vbar[n,d]   (f32 accumulation pre-rounding)
//   out[n,d] = cst[d] + (deg[n]? rsqrt(deg[n]):0) * sum_{e:col=n} vbar2[row_e, d]
//
// Round-13 = round-11 (best, 109.25us) minus the bucketScan launch:
//   fill computes bucketBase via LDS scan of colsum (proven in round 12);
//   sort computes its own [s,e) via colsum partial sums (proven in round 12).
// Round-12's LDS-atomic gather REVERTED (353us: 782 blocks / 21% occupancy
// serialized on LDS-atomic chains; per-node register gather wins).

#define GRID_EDGE 512
#define MAXBUK 1024   // supports N <= 131072

typedef __attribute__((ext_vector_type(8))) short    short8v;
typedef __attribute__((ext_vector_type(8))) __bf16   bf16x8;
typedef __attribute__((ext_vector_type(4))) float    f32x4;

__device__ __forceinline__ short f2bf(float f) {
    unsigned u = __float_as_uint(f);
    unsigned r = (u + 0x7FFFu + ((u >> 16) & 1u)) >> 16;   // RNE
    return (short)r;
}
__device__ __forceinline__ float bf2f(unsigned short v) {
    return __uint_as_float((unsigned)v << 16);
}

// ---------------------------------------------------------------------------
// K0: pack B fragments + zero g_csum. WTB[((dt*4+kt)*64+l)*8+j] = bf16(wt(k,d)),
//     k = kt*32 + (l>>4)*8 + j, d = dt*16 + (l&15),
//     wt(i,d) = 0.25*sum_h Wv[i*128+32h+d].
// ---------------------------------------------------------------------------
__global__ __launch_bounds__(256) void wt_kernel(const float* __restrict__ Wv,
                                                 short* __restrict__ WTB,
                                                 float* __restrict__ g_csum) {
    int idx = blockIdx.x * 256 + threadIdx.x;
    if (blockIdx.x == 0 && threadIdx.x < 32) g_csum[threadIdx.x] = 0.f;
    if (idx < 512) {
        int l = idx & 63;
        int kt = (idx >> 6) & 3;
        int dt = idx >> 8;
        int d = dt * 16 + (l & 15);
        int kbase = kt * 32 + (l >> 4) * 8;
#pragma unroll
        for (int j = 0; j < 8; j++) {
            int i = kbase + j;
            float w = 0.25f * (Wv[i * 128 + d] + Wv[i * 128 + 32 + d] +
                               Wv[i * 128 + 64 + d] + Wv[i * 128 + 96 + d]);
            WTB[idx * 8 + j] = f2bf(w);
        }
    }
}

// ---------------------------------------------------------------------------
// K1 (fused): blocks [0, VB): vbar (MFMA, unscaled bf16 + csum)
//             blocks [VB, VB+GRID_EDGE): per-block LDS bucket histogram
// ---------------------------------------------------------------------------
__global__ __launch_bounds__(256) void fused_kernel(
    const float* __restrict__ xs, const short* __restrict__ WTB,
    const float* __restrict__ bv, unsigned short* __restrict__ vbarb,
    float* __restrict__ g_csum, int N, int VB,
    const int* __restrict__ ei, int E, int chunk, int NBUK,
    unsigned* __restrict__ bcnt_pb)
{
    __shared__ float csum_lds[32];
    __shared__ unsigned h[MAXBUK];
    const int tid = threadIdx.x;

    if ((int)blockIdx.x >= VB) {
        // ---------------- histogram part ----------------
        const int p = blockIdx.x - VB;
        for (int k = tid; k < NBUK; k += 256) h[k] = 0u;
        __syncthreads();
        const int e0 = p * chunk;
        const int e1 = min(E, e0 + chunk);
        for (int e = e0 + tid; e < e1; e += 256)
            atomicAdd(&h[ei[E + e] >> 7], 1u);
        __syncthreads();
        unsigned* dst = bcnt_pb + (size_t)p * NBUK;
        for (int k = tid; k < NBUK; k += 256) dst[k] = h[k];
        return;
    }

    // ---------------- vbar part ----------------
    if (tid < 32) csum_lds[tid] = 0.f;

    const int lane = tid & 63;
    const int col = lane & 15;
    const int grp = lane >> 4;

    short8v bfr[2][4];
    const short8v* wtb = (const short8v*)WTB;
#pragma unroll
    for (int dt = 0; dt < 2; dt++)
#pragma unroll
        for (int kt = 0; kt < 4; kt++)
            bfr[dt][kt] = wtb[(dt * 4 + kt) * 64 + lane];

    const int d0 = col, d1 = col + 16;
    const float bb0 = 0.25f * (bv[d0] + bv[32 + d0] + bv[64 + d0] + bv[96 + d0]);
    const float bb1 = 0.25f * (bv[d1] + bv[32 + d1] + bv[64 + d1] + bv[96 + d1]);

    float cs0 = 0.f, cs1 = 0.f;
    const int ntiles = (N + 15) >> 4;
    const int wglob = blockIdx.x * 4 + (tid >> 6);
    const int nwaves = VB * 4;

    for (int t = wglob; t < ntiles; t += nwaves) {
        const int n0 = t * 16;
        const int rowg = min(n0 + col, N - 1);
        const float* xb = xs + (size_t)rowg * 128 + grp * 8;

        f32x4 alo[4], ahi[4];
#pragma unroll
        for (int kt = 0; kt < 4; kt++) {
            alo[kt] = *(const f32x4*)(xb + kt * 32);
            ahi[kt] = *(const f32x4*)(xb + kt * 32 + 4);
        }

        f32x4 acc0 = {0.f, 0.f, 0.f, 0.f};
        f32x4 acc1 = {0.f, 0.f, 0.f, 0.f};
#pragma unroll
        for (int kt = 0; kt < 4; kt++) {
            short8v af;
            af[0] = f2bf(alo[kt][0]); af[1] = f2bf(alo[kt][1]);
            af[2] = f2bf(alo[kt][2]); af[3] = f2bf(alo[kt][3]);
            af[4] = f2bf(ahi[kt][0]); af[5] = f2bf(ahi[kt][1]);
            af[6] = f2bf(ahi[kt][2]); af[7] = f2bf(ahi[kt][3]);
            bf16x8 a = __builtin_bit_cast(bf16x8, af);
            acc0 = __builtin_amdgcn_mfma_f32_16x16x32_bf16(
                a, __builtin_bit_cast(bf16x8, bfr[0][kt]), acc0, 0, 0, 0);
            acc1 = __builtin_amdgcn_mfma_f32_16x16x32_bf16(
                a, __builtin_bit_cast(bf16x8, bfr[1][kt]), acc1, 0, 0, 0);
        }

        const int rbase = n0 + grp * 4;
        const bool full = (n0 + 16 <= N);
#pragma unroll
        for (int r = 0; r < 4; r++) {
            int n = rbase + r;
            if (full || n < N) {
                float v0 = acc0[r] + bb0;
                float v1 = acc1[r] + bb1;
                vbarb[(size_t)n * 32 + d0] = (unsigned short)f2bf(v0);
                vbarb[(size_t)n * 32 + d1] = (unsigned short)f2bf(v1);
                cs0 += v0; cs1 += v1;
            }
        }
    }

    __syncthreads();
    atomicAdd(&csum_lds[d0], cs0);
    atomicAdd(&csum_lds[d1], cs1);
    __syncthreads();
    if (tid < 32) atomicAdd(&g_csum[tid], csum_lds[tid]);
}

// ---------------------------------------------------------------------------
// K2: per-bucket exclusive scan over the 512 blocks in XCD-major logical
// order i (p(i) = (i>>6) + ((i&63)<<3)).  -> partial_pb[bucket][512], colsum.
// ---------------------------------------------------------------------------
__global__ __launch_bounds__(256) void scanPB_kernel(const unsigned* __restrict__ bcnt_pb,
                                                     int NBUK,
                                                     unsigned* __restrict__ partial_pb,
                                                     unsigned* __restrict__ colsum) {
    __shared__ unsigned s[256];
    const int b = blockIdx.x;
    const int tid = threadIdx.x;
    const int i0 = tid * 2, i1 = tid * 2 + 1;
    const int p0 = (i0 >> 6) + ((i0 & 63) << 3);
    const int p1 = (i1 >> 6) + ((i1 & 63) << 3);
    unsigned v0 = bcnt_pb[(size_t)p0 * NBUK + b];
    unsigned v1 = bcnt_pb[(size_t)p1 * NBUK + b];
    unsigned local = v0 + v1;
    s[tid] = local;
    __syncthreads();
    for (int off = 1; off < 256; off <<= 1) {
        unsigned t = (tid >= off) ? s[tid - off] : 0u;
        __syncthreads();
        s[tid] += t;
        __syncthreads();
    }
    unsigned run = s[tid] - local;
    partial_pb[(size_t)b * 512 + i0] = run;
    partial_pb[(size_t)b * 512 + i1] = run + v0;
    if (tid == 255) colsum[b] = s[255];
}

// ---------------------------------------------------------------------------
// K3: fill. Prologue: LDS exclusive scan of colsum -> bucketBase; cursors
// cur[k] = base[k] + partial_pb[k][i(p)], i(p) = (p&7)*64 + (p>>3).
// Then scatter edges to bucket-grouped meta (row | (col&127)<<20).
// ---------------------------------------------------------------------------
__global__ __launch_bounds__(256) void fill_kernel(const int* __restrict__ ei, int E,
                                                   int chunk, int NBUK,
                                                   const unsigned* __restrict__ partial_pb,
                                                   const unsigned* __restrict__ colsum,
                                                   unsigned* __restrict__ sorted) {
    __shared__ unsigned cur[MAXBUK];
    __shared__ unsigned stmp[256];
    const int tid = threadIdx.x;
    const int p = blockIdx.x;
    const int i = (p & 7) * 64 + (p >> 3);

    unsigned v[4], local = 0;
#pragma unroll
    for (int j = 0; j < 4; j++) {
        int k = tid * 4 + j;
        v[j] = (k < NBUK) ? colsum[k] : 0u;
        local += v[j];
    }
    stmp[tid] = local;
    __syncthreads();
    for (int off = 1; off < 256; off <<= 1) {
        unsigned t = (tid >= off) ? stmp[tid - off] : 0u;
        __syncthreads();
        stmp[tid] += t;
        __syncthreads();
    }
    unsigned run = stmp[tid] - local;
#pragma unroll
    for (int j = 0; j < 4; j++) {
        int k = tid * 4 + j;
        if (k < NBUK) cur[k] = run + partial_pb[(size_t)k * 512 + i];
        run += v[j];
    }
    __syncthreads();

    const int e0 = p * chunk;
    const int e1 = min(E, e0 + chunk);
    for (int e = e0 + tid; e < e1; e += 256) {
        int row = ei[e];
        int col = ei[E + e];
        unsigned pos = atomicAdd(&cur[col >> 7], 1u);
        sorted[pos] = (unsigned)row | ((unsigned)(col & 127) << 20);
    }
}

// ---------------------------------------------------------------------------
// K4: per-bucket counting sort + rsd + rowptr + vbar scale (round-11 form;
// [s,e) computed in-kernel from colsum partial sums).
// ---------------------------------------------------------------------------
__global__ __launch_bounds__(256) void sort_kernel(
    const unsigned* __restrict__ colsum, const unsigned* __restrict__ sorted,
    float* __restrict__ rsd, unsigned* __restrict__ rowptr,
    unsigned* __restrict__ sorted2, unsigned short* __restrict__ vbarb,
    int N, int NBUK, int E)
{
    __shared__ unsigned sb[2];
    __shared__ unsigned h[128];
    __shared__ unsigned sc[128];
    __shared__ unsigned cur[128];
    __shared__ float rs_l[128];
    const int tid = threadIdx.x;
    const int b = blockIdx.x;
    if (tid == 0) sb[0] = 0u;
    if (tid < 128) h[tid] = 0u;
    __syncthreads();
    unsigned part = 0;
    for (int k = tid; k < NBUK; k += 256) {
        unsigned c = colsum[k];
        if (k < b) part += c;
        else if (k == b) sb[1] = c;
    }
    atomicAdd(&sb[0], part);
    __syncthreads();
    const unsigned s = sb[0];
    const unsigned e = s + sb[1];

    for (unsigned p = s + (unsigned)tid; p < e; p += 256u)
        atomicAdd(&h[sorted[p] >> 20], 1u);
    __syncthreads();
    if (tid < 128) sc[tid] = h[tid];
    __syncthreads();
    for (int off = 1; off < 128; off <<= 1) {
        unsigned t = 0;
        if (tid < 128 && tid >= off) t = sc[tid - off];
        __syncthreads();
        if (tid < 128) sc[tid] += t;
        __syncthreads();
    }
    if (tid < 128) {
        unsigned ex = sc[tid] - h[tid];
        cur[tid] = ex;
        float rv = h[tid] ? rsqrtf((float)h[tid]) : 0.f;
        rs_l[tid] = rv;
        int n = b * 128 + tid;
        if (n < N) {
            rsd[n] = rv;
            rowptr[n] = s + ex;
        }
    }
    if (b == (int)gridDim.x - 1 && tid == 0) rowptr[N] = (unsigned)E;
    __syncthreads();
    for (unsigned p = s + (unsigned)tid; p < e; p += 256u) {
        unsigned m = sorted[p];
        unsigned pos = atomicAdd(&cur[m >> 20], 1u);
        sorted2[s + pos] = m & 0xFFFFFu;
    }
    // scale vbarb rows of this bucket in place: vbar2 = vbar * rsqrt(deg)
    const int nbase = b * 128;
#pragma unroll
    for (int it = 0; it < 16; it++) {
        int idx = it * 256 + tid;          // 0..4095
        int cl = idx >> 5, d = idx & 31;
        int n = nbase + cl;
        if (n < N) {
            size_t off = (size_t)n * 32 + d;
            vbarb[off] = (unsigned short)f2bf(bf2f(vbarb[off]) * rs_l[cl]);
        }
    }
}

// ---------------------------------------------------------------------------
// K5: per-node gather: out[n,d] = cst[d] + rsd[n] * sum_p bf2f(vbarb[row_p, d])
// ---------------------------------------------------------------------------
__global__ __launch_bounds__(256) void gather_kernel(
    const unsigned* __restrict__ rowptr, const unsigned* __restrict__ sorted2,
    const unsigned short* __restrict__ vbarb, const float* __restrict__ g_csum,
    const float* __restrict__ rsd, float* __restrict__ out, int N, float invN)
{
    const int tid = threadIdx.x;
    const int n = blockIdx.x * 8 + (tid >> 5);
    const int d = tid & 31;
    if (n >= N) return;
    const unsigned s = rowptr[n];
    const unsigned e = rowptr[n + 1];
    float acc = 0.f;
    for (unsigned p0 = s; p0 < e; p0 += 32) {
        const int cnt = (int)min(32u, e - p0);
        unsigned pe = p0 + (unsigned)d;
        if (pe >= e) pe = e - 1;
        int m = (int)sorted2[pe];
        int j = 0;
        for (; j + 7 < cnt; j += 8) {
            int r0 = __shfl(m, j + 0, 32);
            int r1 = __shfl(m, j + 1, 32);
            int r2 = __shfl(m, j + 2, 32);
            int r3 = __shfl(m, j + 3, 32);
            int r4 = __shfl(m, j + 4, 32);
            int r5 = __shfl(m, j + 5, 32);
            int r6 = __shfl(m, j + 6, 32);
            int r7 = __shfl(m, j + 7, 32);
            float f0 = bf2f(vbarb[(size_t)r0 * 32 + d]);
            float f1 = bf2f(vbarb[(size_t)r1 * 32 + d]);
            float f2 = bf2f(vbarb[(size_t)r2 * 32 + d]);
            float f3 = bf2f(vbarb[(size_t)r3 * 32 + d]);
            float f4 = bf2f(vbarb[(size_t)r4 * 32 + d]);
            float f5 = bf2f(vbarb[(size_t)r5 * 32 + d]);
            float f6 = bf2f(vbarb[(size_t)r6 * 32 + d]);
            float f7 = bf2f(vbarb[(size_t)r7 * 32 + d]);
            acc += ((f0 + f1) + (f2 + f3)) + ((f4 + f5) + (f6 + f7));
        }
        for (; j < cnt; j++) {
            int r0 = __shfl(m, j, 32);
            acc += bf2f(vbarb[(size_t)r0 * 32 + d]);
        }
    }
    out[(size_t)n * 32 + d] = g_csum[d] * invN + rsd[n] * acc;
}

// ---------------------------------------------------------------------------
extern "C" void kernel_launch(void* const* d_in, const int* in_sizes, int n_in,
                              void* d_out, int out_size, void* d_ws, size_t ws_size,
                              hipStream_t stream) {
    const float* xs = (const float*)d_in[1];
    const int*   ei = (const int*)d_in[2];
    const float* Wv = (const float*)d_in[7];
    const float* bv = (const float*)d_in[8];
    float* out = (float*)d_out;

    const int N = in_sizes[0] / 128;
    const int E = in_sizes[2] / 2;
    const int NBUK = (N + 127) >> 7;                 // 782
    const int chunk = (E + GRID_EDGE - 1) / GRID_EDGE;
    const int VB = 1563;                             // vbar blocks in fused kernel

    char* ws = (char*)d_ws;
    size_t o = 0;
    unsigned short* vbarb = (unsigned short*)(ws + o); o += (size_t)N * 32 * 2;
    o = (o + 15) & ~(size_t)15;
    float*    rsd        = (float*)(ws + o);    o += (size_t)N * 4;
    float*    g_csum     = (float*)(ws + o);    o += 32 * 4;
    unsigned* rowptr     = (unsigned*)(ws + o); o += (size_t)(N + 1) * 4;
    unsigned* bcnt_pb    = (unsigned*)(ws + o); o += (size_t)GRID_EDGE * NBUK * 4;
    unsigned* partial_pb = (unsigned*)(ws + o); o += (size_t)NBUK * 512 * 4;
    unsigned* colsum     = (unsigned*)(ws + o); o += (size_t)NBUK * 4;
    o = (o + 15) & ~(size_t)15;
    short*    WTB        = (short*)(ws + o);    o += 4096 * 2;
    unsigned* sorted     = (unsigned*)(ws + o); o += (size_t)E * 4;
    unsigned* sorted2    = (unsigned*)(ws + o); o += (size_t)E * 4;

    wt_kernel<<<2, 256, 0, stream>>>(Wv, WTB, g_csum);
    fused_kernel<<<VB + GRID_EDGE, 256, 0, stream>>>(xs, WTB, bv, vbarb, g_csum,
                                                     N, VB, ei, E, chunk, NBUK, bcnt_pb);
    scanPB_kernel<<<NBUK, 256, 0, stream>>>(bcnt_pb, NBUK, partial_pb, colsum);
    fill_kernel<<<GRID_EDGE, 256, 0, stream>>>(ei, E, chunk, NBUK, partial_pb,
                                               colsum, sorted);
    sort_kernel<<<NBUK, 256, 0, stream>>>(colsum, sorted, rsd, rowptr,
                                          sorted2, vbarb, N, NBUK, E);
    gather_kernel<<<(N + 7) / 8, 256, 0, stream>>>(rowptr, sorted2, vbarb, g_csum,
                                                   rsd, out, N, 1.0f / (float)N);
}